// Round 5
// baseline (95.120 us; speedup 1.0000x reference)
//
#include <hip/hip_runtime.h>
#include <hip/hip_bf16.h>

#define NPIX 9216      // H*W
#define NB 2
#define NC 64
#define JB 72          // 128-j blocks per (b,ic)
#define CHUNK_I 128    // i's staged in LDS per chunk

typedef __attribute__((ext_vector_type(4))) short s16x4;
typedef __attribute__((ext_vector_type(8))) short s16x8;
typedef __attribute__((ext_vector_type(4))) float fp32x4;
typedef __attribute__((ext_vector_type(16))) float f32x16;

#define LOG2E 1.44269504088896340736f

#if defined(__has_builtin)
#if __has_builtin(__builtin_amdgcn_exp2f)
#define EXP2(x) __builtin_amdgcn_exp2f(x)
#endif
#endif
#ifndef EXP2
#define EXP2(x) exp2f(x)
#endif

__device__ __forceinline__ short bf16b(float f) {
  unsigned u = __builtin_bit_cast(unsigned, f);
  u += 0x7FFFu + ((u >> 16) & 1u);          // RNE, no NaN in this data
  return (short)(u >> 16);
}

__device__ __forceinline__ int cvtpk(float a, float b) {
  int r;
  asm("v_cvt_pk_bf16_f32 %0, %1, %2" : "=v"(r) : "v"(a), "v"(b));
  return r;
}

// ---------------- Stage 1: per-pixel 1x1 convs -> q (pre-scaled by log2e), k
// (bf16 [b][pix][8]) and V packed for the 32x32x16 PV-MFMA B-operand:
// vbf[b][blk=i/32][ks2][s2][c64][t8] with i = 32*blk + 16*ks + 4*s + (t&3) + 8*(t>>2).
// Block = 512 threads = 64 j x 8 channel-groups (8 out-ch each).
__global__ __launch_bounds__(512) void cvt_qkv_kernel(
    const float* __restrict__ rv, const float* __restrict__ bev,
    const float* __restrict__ Wq, const float* __restrict__ bq,
    const float* __restrict__ Wk, const float* __restrict__ bk,
    const float* __restrict__ Wv, const float* __restrict__ bv,
    short* __restrict__ qbf, short* __restrict__ kbf, short* __restrict__ vbf)
{
  __shared__ float wlds[5120];       // Wv [64][64] @0, Wq*log2e [8][64] @4096, Wk [8][64] @4608
  __shared__ short vlds[64][72];     // v transpose buffer [c][j] (+pad)
  const int tid = threadIdx.x;
  const int jb = blockIdx.x, b = blockIdx.y;
  const int jbase = jb * 64;

  for (int idx = tid; idx < 5120; idx += 512)
    wlds[idx] = (idx < 4096) ? Wv[idx]
              : (idx < 4608) ? Wq[idx - 4096] * LOG2E
                             : Wk[idx - 4608];
  __syncthreads();

  const int jl = tid & 63, cg = tid >> 6;   // cg 0..7
  const float* xr = rv  + (size_t)b * NC * NPIX + jbase + jl;
  const float* xb = bev + (size_t)b * NC * NPIX + jbase + jl;

  float va[8];
#pragma unroll
  for (int u = 0; u < 8; ++u) va[u] = bv[cg * 8 + u];
  float qk[8];
  if (cg == 0) {
#pragma unroll
    for (int u = 0; u < 8; ++u) qk[u] = bq[u] * LOG2E;
  } else if (cg == 1) {
#pragma unroll
    for (int u = 0; u < 8; ++u) qk[u] = bk[u];
  }

  for (int c2 = 0; c2 < 32; ++c2) {
    const int c = c2 * 2;
    const float x0 = xr[(size_t)c * NPIX], x1 = xr[(size_t)(c + 1) * NPIX];
#pragma unroll
    for (int u = 0; u < 8; ++u) {
      float2 w = *(const float2*)&wlds[(cg * 8 + u) * 64 + c];
      va[u] = fmaf(w.y, x1, fmaf(w.x, x0, va[u]));
    }
    if (cg == 0) {
      const float y0 = xb[(size_t)c * NPIX], y1 = xb[(size_t)(c + 1) * NPIX];
#pragma unroll
      for (int u = 0; u < 8; ++u) {
        float2 w = *(const float2*)&wlds[4096 + u * 64 + c];
        qk[u] = fmaf(w.y, y1, fmaf(w.x, y0, qk[u]));
      }
    } else if (cg == 1) {
#pragma unroll
      for (int u = 0; u < 8; ++u) {
        float2 w = *(const float2*)&wlds[4608 + u * 64 + c];
        qk[u] = fmaf(w.y, x1, fmaf(w.x, x0, qk[u]));
      }
    }
  }

  if (cg == 0) {
    s16x8 qp;
#pragma unroll
    for (int u = 0; u < 8; ++u) qp[u] = bf16b(qk[u]);
    ((s16x8*)qbf)[(size_t)b * NPIX + jbase + jl] = qp;
  } else if (cg == 1) {
    s16x8 kp;
#pragma unroll
    for (int u = 0; u < 8; ++u) kp[u] = bf16b(qk[u]);
    ((s16x8*)kbf)[(size_t)b * NPIX + jbase + jl] = kp;
  }
#pragma unroll
  for (int u = 0; u < 8; ++u) vlds[cg * 8 + u][jl] = bf16b(va[u]);
  __syncthreads();

  s16x8* vout = (s16x8*)vbf + ((size_t)b * 288 + jb * 2) * 256;
  const int blk_l = tid >> 8;               // which 32-i block of the 64 j's
  const int rem = tid & 255;
  const int ks = rem >> 7, s = (rem >> 6) & 1, c = rem & 63;
  const int i0 = blk_l * 32 + ks * 16 + s * 4;
  s16x8 vv;
#pragma unroll
  for (int t = 0; t < 8; ++t)
    vv[t] = vlds[c][i0 + (t & 3) + 8 * (t >> 2)];
  vout[blk_l * 256 + (ks * 2 + s) * 64 + c] = vv;
}

// ---------------- Stage 2: flash attention, 32x32x16 MFMA.
// Block = 256 threads = 4 waves, each wave owns 32 j (jbase = jb*128 + wid*32).
// Per 32-i unit: 1 score MFMA (A = streamed q rows, B = wave-fixed k cols,
// K=16 with d=0..7 real / 8..15 zeroed on B), exp2 on the 16 D regs,
// 8 cvt_pk -> PV A-frags (ZERO cross-lane: D rows (r&3)+8(r>>2)+4hi match the
// A k-map 4s+(t&3)+8(t>>2) exactly), 4 PV MFMAs over (kstep, c-tile).
// den = VALU sum of e's (+ one shfl_xor(32) at the end).
// Single 18.4 KB LDS buffer, T14 reg-staged (loads for ch+1 issue before
// compute of ch; ds_writes after the second barrier).
__global__ __launch_bounds__(256, 4) void attn_kernel(
    const short* __restrict__ qbf, const short* __restrict__ kbf,
    const short* __restrict__ vbf,
    short* __restrict__ numws, float* __restrict__ denws, int nic)
{
  __shared__ s16x8 lq8[128];    // 2 KB: streamed q rows (16B each)
  __shared__ s16x8 lv8[1024];   // 16 KB: [u4][ks2][s2][c64]

  const int bid = blockIdx.x;
  const int jb = bid % JB;
  const int rest = bid / JB;
  const int b = rest % NB;
  const int ic = rest / NB;
  const int tid = threadIdx.x;        // 0..255
  const int wid = tid >> 6, lane = tid & 63;
  const int l31 = lane & 31, hi = lane >> 5;
  const int jbase = jb * 128 + wid * 32;
  const int ichunk = NPIX / nic;
  const int ibase = ic * ichunk;
  const int nch = ichunk / CHUNK_I;

  const short* qrow = qbf + ((size_t)b * NPIX) * 8;
  const short* krow = kbf + ((size_t)b * NPIX) * 8;
  const s16x8* q8 = (const s16x8*)qrow;
  const s16x8* v8 = (const s16x8*)vbf + (size_t)b * 288 * 256;

  const f32x16 z16 = {0.f};

  // B-operand of score MFMA (wave-fixed k-data): lane (j=l31, s=hi):
  // elems 0-3 = k[j][4*hi .. 4*hi+3] (k-dim 4s+t), elems 4-7 = ZERO (k>=8).
  s16x8 kf;
  {
    const s16x4 kh = *(const s16x4*)(krow + ((size_t)(jbase + l31)) * 8 + hi * 4);
    kf[0] = kh[0]; kf[1] = kh[1]; kf[2] = kh[2]; kf[3] = kh[3];
    kf[4] = 0; kf[5] = 0; kf[6] = 0; kf[7] = 0;
  }

  f32x16 acc0 = z16, acc1 = z16;
  float den = 0.f;

  s16x8 vreg[4], qreg;
  auto loadregs = [&](int ch) {
    const int cbase = ibase + ch * CHUNK_I;
    const size_t vb = ((size_t)(cbase >> 5)) * 256;
#pragma unroll
    for (int r = 0; r < 4; ++r) vreg[r] = v8[vb + r * 256 + tid];
    if (tid < 128) qreg = q8[cbase + tid];
  };
  auto writeLDS = [&]() {
#pragma unroll
    for (int r = 0; r < 4; ++r) lv8[r * 256 + tid] = vreg[r];
    if (tid < 128) lq8[tid] = qreg;
  };

  loadregs(0);
  writeLDS();
  const int vl = hi * 64 + l31;

  for (int ch = 0; ch < nch; ++ch) {
    __syncthreads();                       // staged chunk visible
    if (ch + 1 < nch) loadregs(ch + 1);    // issue next loads (hidden by compute)
#pragma unroll
    for (int u = 0; u < 4; ++u) {
      // A-operand (streamed q): elems 0-3 = q[i][4*hi..+3]; 4-7 pair with B zeros.
      const s16x4 qh = *(const s16x4*)((const short*)lq8 + (u * 32 + l31) * 8 + hi * 4);
      s16x8 af;
      af[0] = qh[0]; af[1] = qh[1]; af[2] = qh[2]; af[3] = qh[3];
      af[4] = 0; af[5] = 0; af[6] = 0; af[7] = 0;
      const f32x16 S = __builtin_amdgcn_mfma_f32_32x32x16_bf16(af, kf, z16, 0, 0, 0);
      const float e0 = EXP2(S[0]),  e1 = EXP2(S[1]),  e2 = EXP2(S[2]),  e3 = EXP2(S[3]);
      const float e4 = EXP2(S[4]),  e5 = EXP2(S[5]),  e6 = EXP2(S[6]),  e7 = EXP2(S[7]);
      const float e8 = EXP2(S[8]),  e9 = EXP2(S[9]),  eA = EXP2(S[10]), eB = EXP2(S[11]);
      const float eC = EXP2(S[12]), eD = EXP2(S[13]), eE = EXP2(S[14]), eF = EXP2(S[15]);
      den += (((e0 + e1) + (e2 + e3)) + ((e4 + e5) + (e6 + e7)))
           + (((e8 + e9) + (eA + eB)) + ((eC + eD) + (eE + eF)));
      int4 p0i, p1i;
      p0i.x = cvtpk(e0, e1); p0i.y = cvtpk(e2, e3);
      p0i.z = cvtpk(e4, e5); p0i.w = cvtpk(e6, e7);
      p1i.x = cvtpk(e8, e9); p1i.y = cvtpk(eA, eB);
      p1i.z = cvtpk(eC, eD); p1i.w = cvtpk(eE, eF);
      const s16x8 A0 = __builtin_bit_cast(s16x8, p0i);   // i = 0..15 of unit
      const s16x8 A1 = __builtin_bit_cast(s16x8, p1i);   // i = 16..31
      const s16x8 vf00 = lv8[u * 256 + vl];          // ks0, c-tile0
      const s16x8 vf01 = lv8[u * 256 + 32 + vl];     // ks0, c-tile1
      const s16x8 vf10 = lv8[u * 256 + 128 + vl];    // ks1, c-tile0
      const s16x8 vf11 = lv8[u * 256 + 160 + vl];    // ks1, c-tile1
      acc0 = __builtin_amdgcn_mfma_f32_32x32x16_bf16(A0, vf00, acc0, 0, 0, 0);
      acc1 = __builtin_amdgcn_mfma_f32_32x32x16_bf16(A0, vf01, acc1, 0, 0, 0);
      acc0 = __builtin_amdgcn_mfma_f32_32x32x16_bf16(A1, vf10, acc0, 0, 0, 0);
      acc1 = __builtin_amdgcn_mfma_f32_32x32x16_bf16(A1, vf11, acc1, 0, 0, 0);
    }
    __syncthreads();                       // all reads of buffer done
    if (ch + 1 < nch) writeLDS();
  }

  // den: lanes l and l^32 hold complementary i-subsets of the SAME j.
  den += __shfl_xor(den, 32);
  const size_t icb = (size_t)ic * NB + b;
  if (lane < 32) denws[icb * NPIX + jbase + l31] = den;

  // numerator -> bf16 [icb][c][NPIX]; D row = (r&3)+8*(r>>2)+4*hi, col c'=l31.
  uint2* nwb = (uint2*)numws;
#pragma unroll
  for (int qd = 0; qd < 4; ++qd) {
    const int jloc = jbase + 8 * qd + 4 * hi;
    uint2 p;
    p.x = (unsigned)cvtpk(acc0[4 * qd], acc0[4 * qd + 1]);
    p.y = (unsigned)cvtpk(acc0[4 * qd + 2], acc0[4 * qd + 3]);
    nwb[(((icb * 64 + l31) * NPIX) + jloc) >> 2] = p;
    p.x = (unsigned)cvtpk(acc1[4 * qd], acc1[4 * qd + 1]);
    p.y = (unsigned)cvtpk(acc1[4 * qd + 2], acc1[4 * qd + 3]);
    nwb[(((icb * 64 + 32 + l31) * NPIX) + jloc) >> 2] = p;
  }
}

// ---------------- Stage 3: combine i-splits, normalize, add residual.
__global__ __launch_bounds__(256) void combine_kernel(
    const float* __restrict__ bev, const short* __restrict__ numws,
    const float* __restrict__ denws, float* __restrict__ out, int nic)
{
  const int t = blockIdx.x * 256 + threadIdx.x;   // 0..147455 per batch
  const int b = blockIdx.y;
  const int c = t / 2304, j4 = t % 2304;
  const uint2* nw = (const uint2*)numws;
  const fp32x4* dw = (const fp32x4*)denws;
  fp32x4 n = {0.f, 0.f, 0.f, 0.f}, d = {0.f, 0.f, 0.f, 0.f};
  for (int ic = 0; ic < nic; ++ic) {
    const size_t icb = (size_t)ic * NB + b;
    const uint2 u = nw[(icb * 64 + c) * 2304 + j4];
    n[0] += __builtin_bit_cast(float, u.x << 16);
    n[1] += __builtin_bit_cast(float, u.x & 0xFFFF0000u);
    n[2] += __builtin_bit_cast(float, u.y << 16);
    n[3] += __builtin_bit_cast(float, u.y & 0xFFFF0000u);
    d += dw[icb * 2304 + j4];
  }
  const size_t o4 = ((size_t)b * 64 + c) * 2304 + j4;
  const fp32x4 r = ((const fp32x4*)bev)[o4];
  fp32x4 z;
  z[0] = r[0] + n[0] / d[0];
  z[1] = r[1] + n[1] / d[1];
  z[2] = r[2] + n[2] / d[2];
  z[3] = r[3] + n[3] / d[3];
  ((fp32x4*)out)[o4] = z;
}

extern "C" void kernel_launch(void* const* d_in, const int* in_sizes, int n_in,
                              void* d_out, int out_size, void* d_ws, size_t ws_size,
                              hipStream_t stream) {
  const float* rv  = (const float*)d_in[0];
  const float* bev = (const float*)d_in[1];
  const float* Wq  = (const float*)d_in[2];
  const float* bq  = (const float*)d_in[3];
  const float* Wk  = (const float*)d_in[4];
  const float* bk  = (const float*)d_in[5];
  const float* Wv  = (const float*)d_in[6];
  const float* bv  = (const float*)d_in[7];
  float* out = (float*)d_out;

  short* qbf = (short*)d_ws;
  short* kbf = qbf + (size_t)NB * NPIX * 8;
  short* vbf = kbf + (size_t)NB * NPIX * 8;
  float* denws = (float*)(vbf + (size_t)NB * NPIX * 64);

  const size_t fixed = (size_t)NB * NPIX * (8 + 8 + 64) * 2;  // qkv bytes
  int nic = 8;
  while (nic > 1) {
    size_t need = fixed + (size_t)nic * NB * NPIX * 4            // denws (f32)
                        + (size_t)nic * NB * NC * NPIX * 2;      // numws (bf16)
    if (need <= ws_size) break;
    nic >>= 1;
  }
  short* numws = (short*)(denws + (size_t)nic * NB * NPIX);

  cvt_qkv_kernel<<<dim3(JB * 2, NB), 512, 0, stream>>>(
      rv, bev, Wq, bq, Wk, bk, Wv, bv, qbf, kbf, vbf);
  attn_kernel<<<dim3(nic * NB * JB), 256, 0, stream>>>(
      qbf, kbf, vbf, numws, denws, nic);
  combine_kernel<<<dim3(576, NB), 256, 0, stream>>>(
      bev, numws, denws, out, nic);
}

// Round 7
// 85.276 us; speedup vs baseline: 1.1154x; 1.1154x over previous
//
#include <hip/hip_runtime.h>
#include <hip/hip_bf16.h>

#define NPIX 9216      // H*W
#define NB 2
#define NC 64
#define JBLK 36        // 256-j blocks per (b,ic)

typedef __attribute__((ext_vector_type(4))) short s16x4;
typedef __attribute__((ext_vector_type(8))) short s16x8;
typedef __attribute__((ext_vector_type(4))) float fp32x4;
typedef __attribute__((ext_vector_type(16))) float f32x16;

#define LOG2E 1.44269504088896340736f

#if defined(__has_builtin)
#if __has_builtin(__builtin_amdgcn_exp2f)
#define EXP2(x) __builtin_amdgcn_exp2f(x)
#endif
#endif
#ifndef EXP2
#define EXP2(x) exp2f(x)
#endif

__device__ __forceinline__ short bf16b(float f) {
  unsigned u = __builtin_bit_cast(unsigned, f);
  u += 0x7FFFu + ((u >> 16) & 1u);          // RNE, no NaN in this data
  return (short)(u >> 16);
}

__device__ __forceinline__ int cvtpk(float a, float b) {
  int r;
  asm("v_cvt_pk_bf16_f32 %0, %1, %2" : "=v"(r) : "v"(a), "v"(b));
  return r;
}

// ---------------- Stage 1: per-pixel 1x1 convs -> q (pre-scaled by log2e), k
// (bf16 [b][pix][8]) and V packed for the 32x32x16 PV-MFMA B-operand:
// vbf[b][blk=i/32][ks2][s2][c64][t8], i = 32*blk + 16*ks + 4*s + (t&3) + 8*(t>>2).
// Block = 512 threads = 64 i-pixels x 8 channel-groups.  (verified r4/r5)
__global__ __launch_bounds__(512) void cvt_qkv_kernel(
    const float* __restrict__ rv, const float* __restrict__ bev,
    const float* __restrict__ Wq, const float* __restrict__ bq,
    const float* __restrict__ Wk, const float* __restrict__ bk,
    const float* __restrict__ Wv, const float* __restrict__ bv,
    short* __restrict__ qbf, short* __restrict__ kbf, short* __restrict__ vbf)
{
  __shared__ float wlds[5120];       // Wv [64][64] @0, Wq*log2e @4096, Wk @4608
  __shared__ short vlds[64][72];     // v transpose buffer [c][j] (+pad)
  const int tid = threadIdx.x;
  const int jb = blockIdx.x, b = blockIdx.y;
  const int jbase = jb * 64;

  for (int idx = tid; idx < 5120; idx += 512)
    wlds[idx] = (idx < 4096) ? Wv[idx]
              : (idx < 4608) ? Wq[idx - 4096] * LOG2E
                             : Wk[idx - 4608];
  __syncthreads();

  const int jl = tid & 63, cg = tid >> 6;   // cg 0..7
  const float* xr = rv  + (size_t)b * NC * NPIX + jbase + jl;
  const float* xb = bev + (size_t)b * NC * NPIX + jbase + jl;

  float va[8];
#pragma unroll
  for (int u = 0; u < 8; ++u) va[u] = bv[cg * 8 + u];
  float qk[8];
  if (cg == 0) {
#pragma unroll
    for (int u = 0; u < 8; ++u) qk[u] = bq[u] * LOG2E;
  } else if (cg == 1) {
#pragma unroll
    for (int u = 0; u < 8; ++u) qk[u] = bk[u];
  }

  for (int c2 = 0; c2 < 32; ++c2) {
    const int c = c2 * 2;
    const float x0 = xr[(size_t)c * NPIX], x1 = xr[(size_t)(c + 1) * NPIX];
#pragma unroll
    for (int u = 0; u < 8; ++u) {
      float2 w = *(const float2*)&wlds[(cg * 8 + u) * 64 + c];
      va[u] = fmaf(w.y, x1, fmaf(w.x, x0, va[u]));
    }
    if (cg == 0) {
      const float y0 = xb[(size_t)c * NPIX], y1 = xb[(size_t)(c + 1) * NPIX];
#pragma unroll
      for (int u = 0; u < 8; ++u) {
        float2 w = *(const float2*)&wlds[4096 + u * 64 + c];
        qk[u] = fmaf(w.y, y1, fmaf(w.x, y0, qk[u]));
      }
    } else if (cg == 1) {
#pragma unroll
      for (int u = 0; u < 8; ++u) {
        float2 w = *(const float2*)&wlds[4608 + u * 64 + c];
        qk[u] = fmaf(w.y, x1, fmaf(w.x, x0, qk[u]));
      }
    }
  }

  if (cg == 0) {
    s16x8 qp;
#pragma unroll
    for (int u = 0; u < 8; ++u) qp[u] = bf16b(qk[u]);
    ((s16x8*)qbf)[(size_t)b * NPIX + jbase + jl] = qp;
  } else if (cg == 1) {
    s16x8 kp;
#pragma unroll
    for (int u = 0; u < 8; ++u) kp[u] = bf16b(qk[u]);
    ((s16x8*)kbf)[(size_t)b * NPIX + jbase + jl] = kp;
  }
#pragma unroll
  for (int u = 0; u < 8; ++u) vlds[cg * 8 + u][jl] = bf16b(va[u]);
  __syncthreads();

  s16x8* vout = (s16x8*)vbf + ((size_t)b * 288 + jb * 2) * 256;
  const int blk_l = tid >> 8;               // which 32-i block of the 64 pix
  const int rem = tid & 255;
  const int ks = rem >> 7, s = (rem >> 6) & 1, c = rem & 63;
  const int i0 = blk_l * 32 + ks * 16 + s * 4;
  s16x8 vv;
#pragma unroll
  for (int t = 0; t < 8; ++t)
    vv[t] = vlds[c][i0 + (t & 3) + 8 * (t >> 2)];
  vout[blk_l * 256 + (ks * 2 + s) * 64 + c] = vv;
}

// ---------------- Stage 2: flash attention, 32x32x16, barrier-free main loop.
// V (1.18 MB/batch) is L2-resident: waves read V/q fragments directly from
// global (coalesced 512B runs). Each wave owns TWO 32-j tiles (jA, jB=jA+128)
// sharing every V/q fragment. Tile A is processed fully (exp/pack/PV) before
// tile B's score is consumed, so only one 16-reg S is live at a time (no
// launch_bounds spill — that was round 6's failure zone).
// Tail: LDS transpose -> coalesced bf16 numws [icb][c][NPIX]; denws [icb][NPIX].
template <int NCH>
__global__ __launch_bounds__(256) void attn_kernel(
    const short* __restrict__ qbf, const short* __restrict__ kbf,
    const short* __restrict__ vbf,
    short* __restrict__ numws, float* __restrict__ denws)
{
  __shared__ ushort nbuf[128][66];

  const int bid = blockIdx.x;
  const int jb = bid % JBLK;
  const int rest = bid / JBLK;
  const int b = rest % NB;
  const int ic = rest / NB;
  const int tid = threadIdx.x;        // 0..255
  const int wid = tid >> 6, lane = tid & 63;
  const int l31 = lane & 31, hi = lane >> 5;
  const int jA = jb * 256 + wid * 32;
  const int jB = jA + 128;
  const int ibase = ic * (NCH * 32);

  const short* qrow = qbf + (size_t)b * NPIX * 8;
  const short* krow = kbf + (size_t)b * NPIX * 8;
  const s16x8* v8 = (const s16x8*)vbf + (size_t)b * 288 * 256;

  const f32x16 z16 = {0.f};

  // Score B-operands (wave-fixed): lane (j=l31, s=hi): elems 0-3 =
  // k[jX+l31][4hi..4hi+3], elems 4-7 = ZERO (k>=8 of the K=16 MFMA).
  s16x8 kfA, kfB;
  {
    const s16x4 ka = *(const s16x4*)(krow + (size_t)(jA + l31) * 8 + hi * 4);
    const s16x4 kb = *(const s16x4*)(krow + (size_t)(jB + l31) * 8 + hi * 4);
    kfA[0] = ka[0]; kfA[1] = ka[1]; kfA[2] = ka[2]; kfA[3] = ka[3];
    kfA[4] = 0; kfA[5] = 0; kfA[6] = 0; kfA[7] = 0;
    kfB[0] = kb[0]; kfB[1] = kb[1]; kfB[2] = kb[2]; kfB[3] = kb[3];
    kfB[4] = 0; kfB[5] = 0; kfB[6] = 0; kfB[7] = 0;
  }

  f32x16 accA0 = z16, accA1 = z16, accB0 = z16, accB1 = z16;
  float denA = 0.f, denB = 0.f;
  const int vl = hi * 64 + l31;

  for (int u = 0; u < NCH; ++u) {
    const size_t iu = (size_t)(ibase >> 5) + u;
    // A-operand (q rows, shared by both tiles): elems 0-3 = q[i][4hi..+3].
    const s16x4 qh = *(const s16x4*)(qrow + (size_t)(ibase + u * 32 + l31) * 8 + hi * 4);
    s16x8 af;
    af[0] = qh[0]; af[1] = qh[1]; af[2] = qh[2]; af[3] = qh[3];
    af[4] = 0; af[5] = 0; af[6] = 0; af[7] = 0;
    // V fragments (shared by both tiles), coalesced from global/L2.
    const s16x8 vf00 = v8[iu * 256 + vl];          // ks0, c 0-31
    const s16x8 vf01 = v8[iu * 256 + 32 + vl];     // ks0, c 32-63
    const s16x8 vf10 = v8[iu * 256 + 128 + vl];    // ks1, c 0-31
    const s16x8 vf11 = v8[iu * 256 + 160 + vl];    // ks1, c 32-63

    // ---- tile A
    {
      const f32x16 S = __builtin_amdgcn_mfma_f32_32x32x16_bf16(af, kfA, z16, 0, 0, 0);
      const float e0 = EXP2(S[0]),  e1 = EXP2(S[1]),  e2 = EXP2(S[2]),  e3 = EXP2(S[3]);
      const float e4 = EXP2(S[4]),  e5 = EXP2(S[5]),  e6 = EXP2(S[6]),  e7 = EXP2(S[7]);
      const float e8 = EXP2(S[8]),  e9 = EXP2(S[9]),  eA = EXP2(S[10]), eB = EXP2(S[11]);
      const float eC = EXP2(S[12]), eD = EXP2(S[13]), eE = EXP2(S[14]), eF = EXP2(S[15]);
      denA += (((e0 + e1) + (e2 + e3)) + ((e4 + e5) + (e6 + e7)))
            + (((e8 + e9) + (eA + eB)) + ((eC + eD) + (eE + eF)));
      int4 p0i, p1i;
      p0i.x = cvtpk(e0, e1); p0i.y = cvtpk(e2, e3);
      p0i.z = cvtpk(e4, e5); p0i.w = cvtpk(e6, e7);
      p1i.x = cvtpk(e8, e9); p1i.y = cvtpk(eA, eB);
      p1i.z = cvtpk(eC, eD); p1i.w = cvtpk(eE, eF);
      const s16x8 A0 = __builtin_bit_cast(s16x8, p0i);   // i 0..15 of unit
      const s16x8 A1 = __builtin_bit_cast(s16x8, p1i);   // i 16..31
      accA0 = __builtin_amdgcn_mfma_f32_32x32x16_bf16(A0, vf00, accA0, 0, 0, 0);
      accA1 = __builtin_amdgcn_mfma_f32_32x32x16_bf16(A0, vf01, accA1, 0, 0, 0);
      accA0 = __builtin_amdgcn_mfma_f32_32x32x16_bf16(A1, vf10, accA0, 0, 0, 0);
      accA1 = __builtin_amdgcn_mfma_f32_32x32x16_bf16(A1, vf11, accA1, 0, 0, 0);
    }
    // ---- tile B
    {
      const f32x16 S = __builtin_amdgcn_mfma_f32_32x32x16_bf16(af, kfB, z16, 0, 0, 0);
      const float e0 = EXP2(S[0]),  e1 = EXP2(S[1]),  e2 = EXP2(S[2]),  e3 = EXP2(S[3]);
      const float e4 = EXP2(S[4]),  e5 = EXP2(S[5]),  e6 = EXP2(S[6]),  e7 = EXP2(S[7]);
      const float e8 = EXP2(S[8]),  e9 = EXP2(S[9]),  eA = EXP2(S[10]), eB = EXP2(S[11]);
      const float eC = EXP2(S[12]), eD = EXP2(S[13]), eE = EXP2(S[14]), eF = EXP2(S[15]);
      denB += (((e0 + e1) + (e2 + e3)) + ((e4 + e5) + (e6 + e7)))
            + (((e8 + e9) + (eA + eB)) + ((eC + eD) + (eE + eF)));
      int4 p0i, p1i;
      p0i.x = cvtpk(e0, e1); p0i.y = cvtpk(e2, e3);
      p0i.z = cvtpk(e4, e5); p0i.w = cvtpk(e6, e7);
      p1i.x = cvtpk(e8, e9); p1i.y = cvtpk(eA, eB);
      p1i.z = cvtpk(eC, eD); p1i.w = cvtpk(eE, eF);
      const s16x8 B0 = __builtin_bit_cast(s16x8, p0i);
      const s16x8 B1 = __builtin_bit_cast(s16x8, p1i);
      accB0 = __builtin_amdgcn_mfma_f32_32x32x16_bf16(B0, vf00, accB0, 0, 0, 0);
      accB1 = __builtin_amdgcn_mfma_f32_32x32x16_bf16(B0, vf01, accB1, 0, 0, 0);
      accB0 = __builtin_amdgcn_mfma_f32_32x32x16_bf16(B1, vf10, accB0, 0, 0, 0);
      accB1 = __builtin_amdgcn_mfma_f32_32x32x16_bf16(B1, vf11, accB1, 0, 0, 0);
    }
  }

  // den: lanes l and l^32 hold complementary i-subsets of the same j.
  denA += __shfl_xor(denA, 32);
  denB += __shfl_xor(denB, 32);
  const size_t icb = (size_t)ic * NB + b;
  if (lane < 32) {
    denws[icb * NPIX + jA + l31] = denA;
    denws[icb * NPIX + jB + l31] = denB;
  }

  // Tail: transpose accs through LDS -> coalesced bf16 [icb][c][NPIX] stores.
  uint2* nwb = (uint2*)numws;
  auto dump = [&](const f32x16& a0, const f32x16& a1, int pass) {
#pragma unroll
    for (int qd = 0; qd < 4; ++qd) {
#pragma unroll
      for (int e = 0; e < 4; ++e) {
        const int row = wid * 32 + 8 * qd + 4 * hi + e;   // j within 128
        nbuf[row][l31] = (ushort)bf16b(a0[4 * qd + e]);
        nbuf[row][32 + l31] = (ushort)bf16b(a1[4 * qd + e]);
      }
    }
    __syncthreads();
    const int jq = tid & 31;
#pragma unroll
    for (int it = 0; it < 8; ++it) {
      const int c = (tid >> 5) + 8 * it;
      const unsigned n0 = nbuf[jq * 4 + 0][c], n1 = nbuf[jq * 4 + 1][c];
      const unsigned n2 = nbuf[jq * 4 + 2][c], n3 = nbuf[jq * 4 + 3][c];
      uint2 p;
      p.x = n0 | (n1 << 16);
      p.y = n2 | (n3 << 16);
      nwb[(((icb * 64 + c) * NPIX) + jb * 256 + pass * 128 + jq * 4) >> 2] = p;
    }
    __syncthreads();
  };
  dump(accA0, accA1, 0);
  dump(accB0, accB1, 1);
}

// ---------------- Stage 3: combine i-splits, normalize, add residual.
__global__ __launch_bounds__(256) void combine_kernel(
    const float* __restrict__ bev, const short* __restrict__ numws,
    const float* __restrict__ denws, float* __restrict__ out, int nic)
{
  const int t = blockIdx.x * 256 + threadIdx.x;   // 0..147455 per batch
  const int b = blockIdx.y;
  const int c = t / 2304, j4 = t % 2304;
  const uint2* nw = (const uint2*)numws;
  const fp32x4* dw = (const fp32x4*)denws;
  fp32x4 n = {0.f, 0.f, 0.f, 0.f}, d = {0.f, 0.f, 0.f, 0.f};
  for (int ic = 0; ic < nic; ++ic) {
    const size_t icb = (size_t)ic * NB + b;
    const uint2 u = nw[(icb * 64 + c) * 2304 + j4];
    n[0] += __builtin_bit_cast(float, u.x << 16);
    n[1] += __builtin_bit_cast(float, u.x & 0xFFFF0000u);
    n[2] += __builtin_bit_cast(float, u.y << 16);
    n[3] += __builtin_bit_cast(float, u.y & 0xFFFF0000u);
    d += dw[icb * 2304 + j4];
  }
  const size_t o4 = ((size_t)b * 64 + c) * 2304 + j4;
  const fp32x4 r = ((const fp32x4*)bev)[o4];
  fp32x4 z;
  z[0] = r[0] + n[0] / d[0];
  z[1] = r[1] + n[1] / d[1];
  z[2] = r[2] + n[2] / d[2];
  z[3] = r[3] + n[3] / d[3];
  ((fp32x4*)out)[o4] = z;
}

extern "C" void kernel_launch(void* const* d_in, const int* in_sizes, int n_in,
                              void* d_out, int out_size, void* d_ws, size_t ws_size,
                              hipStream_t stream) {
  const float* rv  = (const float*)d_in[0];
  const float* bev = (const float*)d_in[1];
  const float* Wq  = (const float*)d_in[2];
  const float* bq  = (const float*)d_in[3];
  const float* Wk  = (const float*)d_in[4];
  const float* bk  = (const float*)d_in[5];
  const float* Wv  = (const float*)d_in[6];
  const float* bv  = (const float*)d_in[7];
  float* out = (float*)d_out;

  short* qbf = (short*)d_ws;
  short* kbf = qbf + (size_t)NB * NPIX * 8;
  short* vbf = kbf + (size_t)NB * NPIX * 8;
  float* denws = (float*)(vbf + (size_t)NB * NPIX * 64);

  const size_t fixed = (size_t)NB * NPIX * (8 + 8 + 64) * 2;  // qkv bytes
  int nic = 16;
  while (nic > 4) {
    size_t need = fixed + (size_t)nic * NB * NPIX * 4            // denws (f32)
                        + (size_t)nic * NB * NC * NPIX * 2;      // numws (bf16)
    if (need <= ws_size) break;
    nic >>= 1;
  }
  short* numws = (short*)(denws + (size_t)nic * NB * NPIX);

  cvt_qkv_kernel<<<dim3(144, NB), 512, 0, stream>>>(
      rv, bev, Wq, bq, Wk, bk, Wv, bv, qbf, kbf, vbf);
  const int nblk = nic * NB * JBLK;
  if (nic == 16) {
    attn_kernel<18><<<dim3(nblk), 256, 0, stream>>>(qbf, kbf, vbf, numws, denws);
  } else if (nic == 8) {
    attn_kernel<36><<<dim3(nblk), 256, 0, stream>>>(qbf, kbf, vbf, numws, denws);
  } else {
    attn_kernel<72><<<dim3(nblk), 256, 0, stream>>>(qbf, kbf, vbf, numws, denws);
  }
  combine_kernel<<<dim3(576, NB), 256, 0, stream>>>(
      bev, numws, denws, out, nic);
}

// Round 8
// 83.621 us; speedup vs baseline: 1.1375x; 1.0198x over previous
//
#include <hip/hip_runtime.h>
#include <hip/hip_bf16.h>

#define NPIX 9216      // H*W
#define NB 2
#define NC 64
#define JBLK 36        // 256-j blocks per (b,ic)

typedef __attribute__((ext_vector_type(4))) short s16x4;
typedef __attribute__((ext_vector_type(8))) short s16x8;
typedef __attribute__((ext_vector_type(2))) float f32x2;
typedef __attribute__((ext_vector_type(4))) float fp32x4;
typedef __attribute__((ext_vector_type(16))) float f32x16;

#define LOG2E 1.44269504088896340736f

__device__ __forceinline__ float exp2fast(float x) {
#if defined(__has_builtin) && __has_builtin(__builtin_amdgcn_exp2f)
  return __builtin_amdgcn_exp2f(x);
#else
  float r; asm("v_exp_f32 %0, %1" : "=v"(r) : "v"(x)); return r;
#endif
}
#define EXP2(x) exp2fast(x)

__device__ __forceinline__ short bf16b(float f) {
  unsigned u = __builtin_bit_cast(unsigned, f);
  u += 0x7FFFu + ((u >> 16) & 1u);          // RNE, no NaN in this data
  return (short)(u >> 16);
}

__device__ __forceinline__ int cvtpk(float a, float b) {
  int r;
  asm("v_cvt_pk_bf16_f32 %0, %1, %2" : "=v"(r) : "v"(a), "v"(b));
  return r;
}

// ---------------- Stage 1: per-pixel 1x1 convs -> q (pre-scaled by log2e), k
// (bf16 [b][pix][8]) and V packed for the 32x32x16 PV-MFMA B-operand:
// vbf[b][blk=i/32][ks2][s2][c64][t8], i = 32*blk + 16*ks + 4*s + (t&3) + 8*(t>>2).
// Block = 512 threads = 64 pixels x 8 channel-groups. rv tile staged in LDS
// (pad-68 rows) so the 64-c loop reads LDS, not strided global.
__global__ __launch_bounds__(512) void cvt_qkv_kernel(
    const float* __restrict__ rv, const float* __restrict__ bev,
    const float* __restrict__ Wq, const float* __restrict__ bq,
    const float* __restrict__ Wk, const float* __restrict__ bk,
    const float* __restrict__ Wv, const float* __restrict__ bv,
    short* __restrict__ qbf, short* __restrict__ kbf, short* __restrict__ vbf)
{
  __shared__ float wlds[5120];            // Wv @0, Wq*log2e @4096, Wk @4608
  __shared__ __align__(16) float xlds[64 * 68];   // rv tile [c][j], pad 68
  __shared__ short vlds[64][72];          // v transpose buffer [c][j] (+pad)
  const int tid = threadIdx.x;
  const int jb = blockIdx.x, b = blockIdx.y;
  const int jbase = jb * 64;

  for (int idx = tid; idx < 5120; idx += 512)
    wlds[idx] = (idx < 4096) ? Wv[idx]
              : (idx < 4608) ? Wq[idx - 4096] * LOG2E
                             : Wk[idx - 4608];
  {
    const int sc = tid >> 3, sk = tid & 7;
    const float* src = rv + (size_t)b * NC * NPIX + (size_t)sc * NPIX + jbase + sk * 8;
    *(float4*)&xlds[sc * 68 + sk * 8]     = *(const float4*)(src);
    *(float4*)&xlds[sc * 68 + sk * 8 + 4] = *(const float4*)(src + 4);
  }
  __syncthreads();

  const int jl = tid & 63, cg = tid >> 6;   // cg 0..7
  const float* xb = bev + (size_t)b * NC * NPIX + jbase + jl;

  float va[8];
#pragma unroll
  for (int u = 0; u < 8; ++u) va[u] = bv[cg * 8 + u];
  float qk[8];
  if (cg == 0) {
#pragma unroll
    for (int u = 0; u < 8; ++u) qk[u] = bq[u] * LOG2E;
  } else if (cg == 1) {
#pragma unroll
    for (int u = 0; u < 8; ++u) qk[u] = bk[u];
  }

  for (int c2 = 0; c2 < 32; ++c2) {
    const int c = c2 * 2;
    const float x0 = xlds[c * 68 + jl], x1 = xlds[(c + 1) * 68 + jl];
#pragma unroll
    for (int u = 0; u < 8; ++u) {
      float2 w = *(const float2*)&wlds[(cg * 8 + u) * 64 + c];
      va[u] = fmaf(w.y, x1, fmaf(w.x, x0, va[u]));
    }
    if (cg == 0) {
      const float y0 = xb[(size_t)c * NPIX], y1 = xb[(size_t)(c + 1) * NPIX];
#pragma unroll
      for (int u = 0; u < 8; ++u) {
        float2 w = *(const float2*)&wlds[4096 + u * 64 + c];
        qk[u] = fmaf(w.y, y1, fmaf(w.x, y0, qk[u]));
      }
    } else if (cg == 1) {
#pragma unroll
      for (int u = 0; u < 8; ++u) {
        float2 w = *(const float2*)&wlds[4608 + u * 64 + c];
        qk[u] = fmaf(w.y, x1, fmaf(w.x, x0, qk[u]));
      }
    }
  }

  if (cg == 0) {
    s16x8 qp;
#pragma unroll
    for (int u = 0; u < 8; ++u) qp[u] = bf16b(qk[u]);
    ((s16x8*)qbf)[(size_t)b * NPIX + jbase + jl] = qp;
  } else if (cg == 1) {
    s16x8 kp;
#pragma unroll
    for (int u = 0; u < 8; ++u) kp[u] = bf16b(qk[u]);
    ((s16x8*)kbf)[(size_t)b * NPIX + jbase + jl] = kp;
  }
#pragma unroll
  for (int u = 0; u < 8; ++u) vlds[cg * 8 + u][jl] = bf16b(va[u]);
  __syncthreads();

  s16x8* vout = (s16x8*)vbf + ((size_t)b * 288 + jb * 2) * 256;
  const int blk_l = tid >> 8;               // which 32-i block of the 64 pix
  const int rem = tid & 255;
  const int ks = rem >> 7, s = (rem >> 6) & 1, c = rem & 63;
  const int i0 = blk_l * 32 + ks * 16 + s * 4;
  s16x8 vv;
#pragma unroll
  for (int t = 0; t < 8; ++t)
    vv[t] = vlds[c][i0 + (t & 3) + 8 * (t >> 2)];
  vout[blk_l * 256 + (ks * 2 + s) * 64 + c] = vv;
}

// ---------------- Stage 2: flash attention, 32x32x16, barrier-free main loop.
// V fragments read directly from global/L2 (coalesced 512B runs); manual
// one-unit-ahead register prefetch hides the ~200-300cy L2 latency under each
// unit's compute. Each wave owns TWO 32-j tiles sharing every V/q fragment.
// Tail: LDS transpose -> coalesced bf16 numws [icb][c][NPIX]; denws [icb][NPIX].
template <int NCH>
__global__ __launch_bounds__(256) void attn_kernel(
    const short* __restrict__ qbf, const short* __restrict__ kbf,
    const short* __restrict__ vbf,
    short* __restrict__ numws, float* __restrict__ denws)
{
  __shared__ ushort nbuf[128][66];

  const int bid = blockIdx.x;
  const int jb = bid % JBLK;
  const int rest = bid / JBLK;
  const int b = rest % NB;
  const int ic = rest / NB;
  const int tid = threadIdx.x;        // 0..255
  const int wid = tid >> 6, lane = tid & 63;
  const int l31 = lane & 31, hi = lane >> 5;
  const int jA = jb * 256 + wid * 32;
  const int jB = jA + 128;
  const int ibase = ic * (NCH * 32);

  const short* qrow = qbf + (size_t)b * NPIX * 8;
  const short* krow = kbf + (size_t)b * NPIX * 8;
  const s16x8* v8 = (const s16x8*)vbf + (size_t)b * 288 * 256;

  const f32x16 z16 = {0.f};

  // Score B-operands (wave-fixed): lane (j=l31, s=hi): elems 0-3 =
  // k[jX+l31][4hi..4hi+3], elems 4-7 = ZERO (k>=8 of the K=16 MFMA).
  s16x8 kfA, kfB;
  {
    const s16x4 ka = *(const s16x4*)(krow + (size_t)(jA + l31) * 8 + hi * 4);
    const s16x4 kb = *(const s16x4*)(krow + (size_t)(jB + l31) * 8 + hi * 4);
    kfA[0] = ka[0]; kfA[1] = ka[1]; kfA[2] = ka[2]; kfA[3] = ka[3];
    kfA[4] = 0; kfA[5] = 0; kfA[6] = 0; kfA[7] = 0;
    kfB[0] = kb[0]; kfB[1] = kb[1]; kfB[2] = kb[2]; kfB[3] = kb[3];
    kfB[4] = 0; kfB[5] = 0; kfB[6] = 0; kfB[7] = 0;
  }

  f32x16 accA0 = z16, accA1 = z16, accB0 = z16, accB1 = z16;
  f32x2 dA = {0.f, 0.f}, dB = {0.f, 0.f};
  const int vl = hi * 64 + l31;

  // Prefetch pipeline: running pointers, one unit ahead.
  const s16x8* vp = v8 + (size_t)(ibase >> 5) * 256 + vl;
  const short* qp = qrow + (size_t)ibase * 8 + l31 * 8 + hi * 4;
  s16x4 qh_n;
  s16x8 vf_n0, vf_n1, vf_n2, vf_n3;
  {
    qh_n = *(const s16x4*)qp;
    vf_n0 = vp[0]; vf_n1 = vp[32]; vf_n2 = vp[128]; vf_n3 = vp[160];
    qp += 256; vp += 256;
  }

  for (int u = 0; u < NCH; ++u) {
    const s16x4 qh = qh_n;
    const s16x8 vf00 = vf_n0, vf01 = vf_n1, vf10 = vf_n2, vf11 = vf_n3;
    if (u + 1 < NCH) {
      qh_n = *(const s16x4*)qp;
      vf_n0 = vp[0]; vf_n1 = vp[32]; vf_n2 = vp[128]; vf_n3 = vp[160];
      qp += 256; vp += 256;
    }
    s16x8 af;
    af[0] = qh[0]; af[1] = qh[1]; af[2] = qh[2]; af[3] = qh[3];
    af[4] = 0; af[5] = 0; af[6] = 0; af[7] = 0;

    // ---- tile A
    {
      const f32x16 S = __builtin_amdgcn_mfma_f32_32x32x16_bf16(af, kfA, z16, 0, 0, 0);
      const float e0 = EXP2(S[0]),  e1 = EXP2(S[1]),  e2 = EXP2(S[2]),  e3 = EXP2(S[3]);
      const float e4 = EXP2(S[4]),  e5 = EXP2(S[5]),  e6 = EXP2(S[6]),  e7 = EXP2(S[7]);
      const float e8 = EXP2(S[8]),  e9 = EXP2(S[9]),  eA = EXP2(S[10]), eB = EXP2(S[11]);
      const float eC = EXP2(S[12]), eD = EXP2(S[13]), eE = EXP2(S[14]), eF = EXP2(S[15]);
      dA += (f32x2){e0, e1}; dA += (f32x2){e2, e3};
      dA += (f32x2){e4, e5}; dA += (f32x2){e6, e7};
      dA += (f32x2){e8, e9}; dA += (f32x2){eA, eB};
      dA += (f32x2){eC, eD}; dA += (f32x2){eE, eF};
      int4 p0i, p1i;
      p0i.x = cvtpk(e0, e1); p0i.y = cvtpk(e2, e3);
      p0i.z = cvtpk(e4, e5); p0i.w = cvtpk(e6, e7);
      p1i.x = cvtpk(e8, e9); p1i.y = cvtpk(eA, eB);
      p1i.z = cvtpk(eC, eD); p1i.w = cvtpk(eE, eF);
      const s16x8 A0 = __builtin_bit_cast(s16x8, p0i);   // i 0..15 of unit
      const s16x8 A1 = __builtin_bit_cast(s16x8, p1i);   // i 16..31
      accA0 = __builtin_amdgcn_mfma_f32_32x32x16_bf16(A0, vf00, accA0, 0, 0, 0);
      accA1 = __builtin_amdgcn_mfma_f32_32x32x16_bf16(A0, vf01, accA1, 0, 0, 0);
      accA0 = __builtin_amdgcn_mfma_f32_32x32x16_bf16(A1, vf10, accA0, 0, 0, 0);
      accA1 = __builtin_amdgcn_mfma_f32_32x32x16_bf16(A1, vf11, accA1, 0, 0, 0);
    }
    // ---- tile B
    {
      const f32x16 S = __builtin_amdgcn_mfma_f32_32x32x16_bf16(af, kfB, z16, 0, 0, 0);
      const float e0 = EXP2(S[0]),  e1 = EXP2(S[1]),  e2 = EXP2(S[2]),  e3 = EXP2(S[3]);
      const float e4 = EXP2(S[4]),  e5 = EXP2(S[5]),  e6 = EXP2(S[6]),  e7 = EXP2(S[7]);
      const float e8 = EXP2(S[8]),  e9 = EXP2(S[9]),  eA = EXP2(S[10]), eB = EXP2(S[11]);
      const float eC = EXP2(S[12]), eD = EXP2(S[13]), eE = EXP2(S[14]), eF = EXP2(S[15]);
      dB += (f32x2){e0, e1}; dB += (f32x2){e2, e3};
      dB += (f32x2){e4, e5}; dB += (f32x2){e6, e7};
      dB += (f32x2){e8, e9}; dB += (f32x2){eA, eB};
      dB += (f32x2){eC, eD}; dB += (f32x2){eE, eF};
      int4 p0i, p1i;
      p0i.x = cvtpk(e0, e1); p0i.y = cvtpk(e2, e3);
      p0i.z = cvtpk(e4, e5); p0i.w = cvtpk(e6, e7);
      p1i.x = cvtpk(e8, e9); p1i.y = cvtpk(eA, eB);
      p1i.z = cvtpk(eC, eD); p1i.w = cvtpk(eE, eF);
      const s16x8 B0 = __builtin_bit_cast(s16x8, p0i);
      const s16x8 B1 = __builtin_bit_cast(s16x8, p1i);
      accB0 = __builtin_amdgcn_mfma_f32_32x32x16_bf16(B0, vf00, accB0, 0, 0, 0);
      accB1 = __builtin_amdgcn_mfma_f32_32x32x16_bf16(B0, vf01, accB1, 0, 0, 0);
      accB0 = __builtin_amdgcn_mfma_f32_32x32x16_bf16(B1, vf10, accB0, 0, 0, 0);
      accB1 = __builtin_amdgcn_mfma_f32_32x32x16_bf16(B1, vf11, accB1, 0, 0, 0);
    }
  }

  // den: lanes l and l^32 hold complementary i-subsets of the same j.
  float denA = dA[0] + dA[1];
  float denB = dB[0] + dB[1];
  denA += __shfl_xor(denA, 32);
  denB += __shfl_xor(denB, 32);
  const size_t icb = (size_t)ic * NB + b;
  if (lane < 32) {
    denws[icb * NPIX + jA + l31] = denA;
    denws[icb * NPIX + jB + l31] = denB;
  }

  // Tail: transpose accs through LDS -> coalesced bf16 [icb][c][NPIX] stores.
  uint2* nwb = (uint2*)numws;
  auto dump = [&](const f32x16& a0, const f32x16& a1, int pass) {
#pragma unroll
    for (int qd = 0; qd < 4; ++qd) {
#pragma unroll
      for (int e = 0; e < 4; ++e) {
        const int row = wid * 32 + 8 * qd + 4 * hi + e;   // j within 128
        nbuf[row][l31] = (ushort)bf16b(a0[4 * qd + e]);
        nbuf[row][32 + l31] = (ushort)bf16b(a1[4 * qd + e]);
      }
    }
    __syncthreads();
    const int jq = tid & 31;
#pragma unroll
    for (int it = 0; it < 8; ++it) {
      const int c = (tid >> 5) + 8 * it;
      const unsigned n0 = nbuf[jq * 4 + 0][c], n1 = nbuf[jq * 4 + 1][c];
      const unsigned n2 = nbuf[jq * 4 + 2][c], n3 = nbuf[jq * 4 + 3][c];
      uint2 p;
      p.x = n0 | (n1 << 16);
      p.y = n2 | (n3 << 16);
      nwb[(((icb * 64 + c) * NPIX) + jb * 256 + pass * 128 + jq * 4) >> 2] = p;
    }
    __syncthreads();
  };
  dump(accA0, accA1, 0);
  dump(accB0, accB1, 1);
}

// ---------------- Stage 3: combine i-splits, normalize, add residual.
__global__ __launch_bounds__(256) void combine_kernel(
    const float* __restrict__ bev, const short* __restrict__ numws,
    const float* __restrict__ denws, float* __restrict__ out, int nic)
{
  const int t = blockIdx.x * 256 + threadIdx.x;   // 0..147455 per batch
  const int b = blockIdx.y;
  const int c = t / 2304, j4 = t % 2304;
  const uint2* nw = (const uint2*)numws;
  const fp32x4* dw = (const fp32x4*)denws;
  fp32x4 n = {0.f, 0.f, 0.f, 0.f}, d = {0.f, 0.f, 0.f, 0.f};
  for (int ic = 0; ic < nic; ++ic) {
    const size_t icb = (size_t)ic * NB + b;
    const uint2 u = nw[(icb * 64 + c) * 2304 + j4];
    n[0] += __builtin_bit_cast(float, u.x << 16);
    n[1] += __builtin_bit_cast(float, u.x & 0xFFFF0000u);
    n[2] += __builtin_bit_cast(float, u.y << 16);
    n[3] += __builtin_bit_cast(float, u.y & 0xFFFF0000u);
    d += dw[icb * 2304 + j4];
  }
  const size_t o4 = ((size_t)b * 64 + c) * 2304 + j4;
  const fp32x4 r = ((const fp32x4*)bev)[o4];
  fp32x4 z;
  z[0] = r[0] + n[0] / d[0];
  z[1] = r[1] + n[1] / d[1];
  z[2] = r[2] + n[2] / d[2];
  z[3] = r[3] + n[3] / d[3];
  ((fp32x4*)out)[o4] = z;
}

extern "C" void kernel_launch(void* const* d_in, const int* in_sizes, int n_in,
                              void* d_out, int out_size, void* d_ws, size_t ws_size,
                              hipStream_t stream) {
  const float* rv  = (const float*)d_in[0];
  const float* bev = (const float*)d_in[1];
  const float* Wq  = (const float*)d_in[2];
  const float* bq  = (const float*)d_in[3];
  const float* Wk  = (const float*)d_in[4];
  const float* bk  = (const float*)d_in[5];
  const float* Wv  = (const float*)d_in[6];
  const float* bv  = (const float*)d_in[7];
  float* out = (float*)d_out;

  short* qbf = (short*)d_ws;
  short* kbf = qbf + (size_t)NB * NPIX * 8;
  short* vbf = kbf + (size_t)NB * NPIX * 8;
  float* denws = (float*)(vbf + (size_t)NB * NPIX * 64);

  const size_t fixed = (size_t)NB * NPIX * (8 + 8 + 64) * 2;  // qkv bytes
  int nic = 16;
  while (nic > 4) {
    size_t need = fixed + (size_t)nic * NB * NPIX * 4            // denws (f32)
                        + (size_t)nic * NB * NC * NPIX * 2;      // numws (bf16)
    if (need <= ws_size) break;
    nic >>= 1;
  }
  short* numws = (short*)(denws + (size_t)nic * NB * NPIX);

  cvt_qkv_kernel<<<dim3(144, NB), 512, 0, stream>>>(
      rv, bev, Wq, bq, Wk, bk, Wv, bv, qbf, kbf, vbf);
  const int nblk = nic * NB * JBLK;
  if (nic == 16) {
    attn_kernel<18><<<dim3(nblk), 256, 0, stream>>>(qbf, kbf, vbf, numws, denws);
  } else if (nic == 8) {
    attn_kernel<36><<<dim3(nblk), 256, 0, stream>>>(qbf, kbf, vbf, numws, denws);
  } else {
    attn_kernel<72><<<dim3(nblk), 256, 0, stream>>>(qbf, kbf, vbf, numws, denws);
  }
  combine_kernel<<<dim3(576, NB), 256, 0, stream>>>(
      bev, numws, denws, out, nic);
}

// Round 10
// 76.464 us; speedup vs baseline: 1.2440x; 1.0936x over previous
//
#include <hip/hip_runtime.h>
#include <hip/hip_bf16.h>

#define NPIX 9216      // H*W
#define NB 2
#define NC 64
#define JB9 36         // 256-j blocks per (b,ic)

typedef __attribute__((ext_vector_type(4))) short s16x4;
typedef __attribute__((ext_vector_type(8))) short s16x8;
typedef __attribute__((ext_vector_type(2))) float f32x2;
typedef __attribute__((ext_vector_type(4))) float fp32x4;
typedef __attribute__((ext_vector_type(16))) float f32x16;

#define LOG2E 1.44269504088896340736f

__device__ __forceinline__ float exp2fast(float x) {
#if defined(__has_builtin) && __has_builtin(__builtin_amdgcn_exp2f)
  return __builtin_amdgcn_exp2f(x);
#else
  float r; asm("v_exp_f32 %0, %1" : "=v"(r) : "v"(x)); return r;
#endif
}
#define EXP2(x) exp2fast(x)

__device__ __forceinline__ short bf16b(float f) {
  unsigned u = __builtin_bit_cast(unsigned, f);
  u += 0x7FFFu + ((u >> 16) & 1u);          // RNE, no NaN in this data
  return (short)(u >> 16);
}

__device__ __forceinline__ unsigned cvtpk(float a, float b) {
  unsigned r;
  asm("v_cvt_pk_bf16_f32 %0, %1, %2" : "=v"(r) : "v"(a), "v"(b));
  return r;
}

// Direct global->LDS DMA, 16B per lane. lds base must be wave-uniform.
__device__ __forceinline__ void gload_lds16(const void* g, void* l) {
  __builtin_amdgcn_global_load_lds(
      (const __attribute__((address_space(1))) unsigned*)g,
      (__attribute__((address_space(3))) unsigned*)l, 16, 0, 0);
}

// ---------------- Stage 1: per-pixel 1x1 convs -> q (pre-scaled by log2e), k
// (bf16 [b][pix][8]) and V packed for the 32x32x16 PV-MFMA B-operand:
// vbf[b][blk=i/32][ks2][s2][c64][t8], i = 32*blk + 16*ks + 4*s + (t&3) + 8*(t>>2).
// (verified r4-r8, unchanged)
__global__ __launch_bounds__(512) void cvt_qkv_kernel(
    const float* __restrict__ rv, const float* __restrict__ bev,
    const float* __restrict__ Wq, const float* __restrict__ bq,
    const float* __restrict__ Wk, const float* __restrict__ bk,
    const float* __restrict__ Wv, const float* __restrict__ bv,
    short* __restrict__ qbf, short* __restrict__ kbf, short* __restrict__ vbf)
{
  __shared__ float wlds[5120];            // Wv @0, Wq*log2e @4096, Wk @4608
  __shared__ __align__(16) float xlds[64 * 68];   // rv tile [c][j], pad 68
  __shared__ short vlds[64][72];          // v transpose buffer [c][j] (+pad)
  const int tid = threadIdx.x;
  const int jb = blockIdx.x, b = blockIdx.y;
  const int jbase = jb * 64;

  for (int idx = tid; idx < 5120; idx += 512)
    wlds[idx] = (idx < 4096) ? Wv[idx]
              : (idx < 4608) ? Wq[idx - 4096] * LOG2E
                             : Wk[idx - 4608];
  {
    const int sc = tid >> 3, sk = tid & 7;
    const float* src = rv + (size_t)b * NC * NPIX + (size_t)sc * NPIX + jbase + sk * 8;
    *(float4*)&xlds[sc * 68 + sk * 8]     = *(const float4*)(src);
    *(float4*)&xlds[sc * 68 + sk * 8 + 4] = *(const float4*)(src + 4);
  }
  __syncthreads();

  const int jl = tid & 63, cg = tid >> 6;   // cg 0..7
  const float* xb = bev + (size_t)b * NC * NPIX + jbase + jl;

  float va[8];
#pragma unroll
  for (int u = 0; u < 8; ++u) va[u] = bv[cg * 8 + u];
  float qk[8];
  if (cg == 0) {
#pragma unroll
    for (int u = 0; u < 8; ++u) qk[u] = bq[u] * LOG2E;
  } else if (cg == 1) {
#pragma unroll
    for (int u = 0; u < 8; ++u) qk[u] = bk[u];
  }

  for (int c2 = 0; c2 < 32; ++c2) {
    const int c = c2 * 2;
    const float x0 = xlds[c * 68 + jl], x1 = xlds[(c + 1) * 68 + jl];
#pragma unroll
    for (int u = 0; u < 8; ++u) {
      float2 w = *(const float2*)&wlds[(cg * 8 + u) * 64 + c];
      va[u] = fmaf(w.y, x1, fmaf(w.x, x0, va[u]));
    }
    if (cg == 0) {
      const float y0 = xb[(size_t)c * NPIX], y1 = xb[(size_t)(c + 1) * NPIX];
#pragma unroll
      for (int u = 0; u < 8; ++u) {
        float2 w = *(const float2*)&wlds[4096 + u * 64 + c];
        qk[u] = fmaf(w.y, y1, fmaf(w.x, y0, qk[u]));
      }
    } else if (cg == 1) {
#pragma unroll
      for (int u = 0; u < 8; ++u) {
        float2 w = *(const float2*)&wlds[4608 + u * 64 + c];
        qk[u] = fmaf(w.y, x1, fmaf(w.x, x0, qk[u]));
      }
    }
  }

  if (cg == 0) {
    s16x8 qp;
#pragma unroll
    for (int u = 0; u < 8; ++u) qp[u] = bf16b(qk[u]);
    ((s16x8*)qbf)[(size_t)b * NPIX + jbase + jl] = qp;
  } else if (cg == 1) {
    s16x8 kp;
#pragma unroll
    for (int u = 0; u < 8; ++u) kp[u] = bf16b(qk[u]);
    ((s16x8*)kbf)[(size_t)b * NPIX + jbase + jl] = kp;
  }
#pragma unroll
  for (int u = 0; u < 8; ++u) vlds[cg * 8 + u][jl] = bf16b(va[u]);
  __syncthreads();

  s16x8* vout = (s16x8*)vbf + ((size_t)b * 288 + jb * 2) * 256;
  const int blk_l = tid >> 8;               // which 32-i block of the 64 pix
  const int rem = tid & 255;
  const int ks = rem >> 7, s = (rem >> 6) & 1, c = rem & 63;
  const int i0 = blk_l * 32 + ks * 16 + s * 4;
  s16x8 vv;
#pragma unroll
  for (int t = 0; t < 8; ++t)
    vv[t] = vlds[c][i0 + (t & 3) + 8 * (t >> 2)];
  vout[blk_l * 256 + (ks * 2 + s) * 64 + c] = vv;
}

// ---------------- Stage 2: flash attention, 32x32x16.  (identical to r9)
// Block = 512 threads = 8 waves; wave owns ONE 32-j tile (jbase = jb*256+wid*32)
// with full 64-c accumulation. V + q staged per 64-i chunk via global_load_lds,
// double buffered, ONE barrier per chunk; all 8 waves share the staged V.
// numws (bf16 pairs, native fragment layout):
//   addr = ((icb*36+jb)*8+wid)*1024 + u*64 + lane  (uint)
//   with jj=j&31: u = (jj>>3)*2 + ((jj>>1)&1) + 8*(c>>5);
//   lane = ((jj>>2)&1)*32 + (c&31); pair = (j even -> lo16, j odd -> hi16).
template <int NCH>   // NCH = number of 64-i chunks per ic
__global__ __launch_bounds__(512) void attn_kernel(
    const short* __restrict__ qbf, const short* __restrict__ kbf,
    const short* __restrict__ vbf,
    unsigned* __restrict__ numws, float* __restrict__ denws)
{
  __shared__ s16x8 lv[2][512];   // 16 KB: per chunk 2 units x [ks2][s2][c64]
  __shared__ s16x8 lq[2][64];    // 2 KB: 64 q rows (16B each)

  const int bid = blockIdx.x;
  const int jb = bid % JB9;
  const int rest = bid / JB9;
  const int b = rest % NB;
  const int ic = rest / NB;
  const int tid = threadIdx.x;        // 0..511
  const int wid = tid >> 6, lane = tid & 63;
  const int l31 = lane & 31, hi = lane >> 5;
  const int jbase = jb * 256 + wid * 32;
  const int ibase = ic * (NCH * 64);

  const s16x8* q8 = (const s16x8*)qbf + (size_t)b * NPIX;
  const short* krow = kbf + (size_t)b * NPIX * 8;
  const s16x8* v8 = (const s16x8*)vbf + (size_t)b * 288 * 256;

  const f32x16 z16 = {0.f};

  // Score B-operand (wave-fixed): lane (j=l31, s=hi): elems 0-3 =
  // k[jbase+l31][4hi..4hi+3], elems 4-7 = ZERO (k>=8 of the K=16 MFMA).
  s16x8 kf;
  {
    const s16x4 ka = *(const s16x4*)(krow + (size_t)(jbase + l31) * 8 + hi * 4);
    kf[0] = ka[0]; kf[1] = ka[1]; kf[2] = ka[2]; kf[3] = ka[3];
    kf[4] = 0; kf[5] = 0; kf[6] = 0; kf[7] = 0;
  }

  f32x16 acc0 = z16, acc1 = z16;
  f32x2 dA = {0.f, 0.f};
  const int vl = hi * 64 + l31;

  auto stage = [&](int ch, int bf) {
    const size_t ebase = ((size_t)(ibase >> 5) + ch * 2) * 256;  // s16x8 entries
    gload_lds16(&v8[ebase + wid * 64 + lane], &lv[bf][wid * 64]);
    if (wid == 0)
      gload_lds16(&q8[(size_t)ibase + ch * 64 + lane], &lq[bf][0]);
  };

  stage(0, 0);
  __syncthreads();           // drains vmcnt(0): buf0 staged

  int buf = 0;
  for (int ch = 0; ch < NCH; ++ch) {
    if (ch + 1 < NCH) stage(ch + 1, buf ^ 1);   // loads fly under compute
#pragma unroll
    for (int u = 0; u < 2; ++u) {
      const s16x4 qh = *(const s16x4*)((const short*)&lq[buf][0] + (u * 32 + l31) * 8 + hi * 4);
      s16x8 af;
      af[0] = qh[0]; af[1] = qh[1]; af[2] = qh[2]; af[3] = qh[3];
      af[4] = 0; af[5] = 0; af[6] = 0; af[7] = 0;
      const s16x8 vf00 = lv[buf][u * 256 + vl];          // ks0, c 0-31
      const s16x8 vf01 = lv[buf][u * 256 + 32 + vl];     // ks0, c 32-63
      const s16x8 vf10 = lv[buf][u * 256 + 128 + vl];    // ks1, c 0-31
      const s16x8 vf11 = lv[buf][u * 256 + 160 + vl];    // ks1, c 32-63

      const f32x16 S = __builtin_amdgcn_mfma_f32_32x32x16_bf16(af, kf, z16, 0, 0, 0);
      const float e0 = EXP2(S[0]),  e1 = EXP2(S[1]),  e2 = EXP2(S[2]),  e3 = EXP2(S[3]);
      const float e4 = EXP2(S[4]),  e5 = EXP2(S[5]),  e6 = EXP2(S[6]),  e7 = EXP2(S[7]);
      const float e8 = EXP2(S[8]),  e9 = EXP2(S[9]),  eA = EXP2(S[10]), eB = EXP2(S[11]);
      const float eC = EXP2(S[12]), eD = EXP2(S[13]), eE = EXP2(S[14]), eF = EXP2(S[15]);
      dA += (f32x2){e0, e1}; dA += (f32x2){e2, e3};
      dA += (f32x2){e4, e5}; dA += (f32x2){e6, e7};
      dA += (f32x2){e8, e9}; dA += (f32x2){eA, eB};
      dA += (f32x2){eC, eD}; dA += (f32x2){eE, eF};
      int4 p0i, p1i;
      p0i.x = cvtpk(e0, e1); p0i.y = cvtpk(e2, e3);
      p0i.z = cvtpk(e4, e5); p0i.w = cvtpk(e6, e7);
      p1i.x = cvtpk(e8, e9); p1i.y = cvtpk(eA, eB);
      p1i.z = cvtpk(eC, eD); p1i.w = cvtpk(eE, eF);
      const s16x8 A0 = __builtin_bit_cast(s16x8, p0i);   // i 0..15 of unit
      const s16x8 A1 = __builtin_bit_cast(s16x8, p1i);   // i 16..31
      acc0 = __builtin_amdgcn_mfma_f32_32x32x16_bf16(A0, vf00, acc0, 0, 0, 0);
      acc1 = __builtin_amdgcn_mfma_f32_32x32x16_bf16(A0, vf01, acc1, 0, 0, 0);
      acc0 = __builtin_amdgcn_mfma_f32_32x32x16_bf16(A1, vf10, acc0, 0, 0, 0);
      acc1 = __builtin_amdgcn_mfma_f32_32x32x16_bf16(A1, vf11, acc1, 0, 0, 0);
    }
    __syncthreads();         // all reads of buf done; next-stage loads drained
    buf ^= 1;
  }

  // den: lanes l and l^32 hold complementary i-subsets of the same j.
  float den = dA[0] + dA[1];
  den += __shfl_xor(den, 32);
  const size_t icb = (size_t)ic * NB + b;
  if (lane < 32) denws[icb * NPIX + jbase + l31] = den;

  // Tail: 16 coalesced uint stores in native fragment layout.
  const size_t wavebase = (((size_t)icb * JB9 + jb) * 8 + wid) * 1024;
#pragma unroll
  for (int qd = 0; qd < 4; ++qd) {
    numws[wavebase + (qd * 2 + 0) * 64 + lane] = cvtpk(acc0[4 * qd + 0], acc0[4 * qd + 1]);
    numws[wavebase + (qd * 2 + 1) * 64 + lane] = cvtpk(acc0[4 * qd + 2], acc0[4 * qd + 3]);
    numws[wavebase + (8 + qd * 2 + 0) * 64 + lane] = cvtpk(acc1[4 * qd + 0], acc1[4 * qd + 1]);
    numws[wavebase + (8 + qd * 2 + 1) * 64 + lane] = cvtpk(acc1[4 * qd + 2], acc1[4 * qd + 3]);
  }
}

// ---------------- Stage 3: combine i-splits, normalize, add residual.
// CORRECTED decode (r9 bug: c/j roles were swapped). For output (c, j):
//   jj = j&31: u = (jj>>3)*2 + ((jj>>1)&1) + 8*(c>>5);
//   lane = ((jj>>2)&1)*32 + (c&31); pair sel = j&1 (even->lo16, odd->hi16).
// Thread = one j-pair x 4 consecutive c: one uint4 read per ic (16B granule,
// 4 consecutive lanes); adjacent threads = consecutive j-pairs -> contiguous
// float2 output runs along j. Block = 16 j-pairs x 16 c-quads = 32 j x 64 c.
__global__ __launch_bounds__(256) void combine_kernel(
    const float* __restrict__ bev, const unsigned* __restrict__ numws,
    const float* __restrict__ denws, float* __restrict__ out, int nic)
{
  const int tid = threadIdx.x;
  const int m = tid & 15;          // j-pair within the 32-j tile: jj = 2m, 2m+1
  const int q = tid >> 4;          // c-quad: c = 4q .. 4q+3
  const int b = blockIdx.y;
  const int j0 = blockIdx.x * 32 + 2 * m;       // even j
  const int jb = j0 >> 8, wid = (j0 >> 5) & 7;
  const int u = (m >> 2) * 2 + (m & 1) + 8 * (q >> 3);
  const int laneoff = ((m >> 1) & 1) * 32 + 4 * (q & 7);

  float n0[4] = {0.f, 0.f, 0.f, 0.f}, n1[4] = {0.f, 0.f, 0.f, 0.f};
  float d0 = 0.f, d1 = 0.f;
  for (int ic = 0; ic < nic; ++ic) {
    const size_t icb = (size_t)ic * NB + b;
    const size_t base = (((icb * JB9 + jb) * 8 + wid) * 1024) + u * 64 + laneoff;
    const uint4 un = *(const uint4*)&numws[base];
    n0[0] += __builtin_bit_cast(float, un.x << 16);
    n1[0] += __builtin_bit_cast(float, un.x & 0xFFFF0000u);
    n0[1] += __builtin_bit_cast(float, un.y << 16);
    n1[1] += __builtin_bit_cast(float, un.y & 0xFFFF0000u);
    n0[2] += __builtin_bit_cast(float, un.z << 16);
    n1[2] += __builtin_bit_cast(float, un.z & 0xFFFF0000u);
    n0[3] += __builtin_bit_cast(float, un.w << 16);
    n1[3] += __builtin_bit_cast(float, un.w & 0xFFFF0000u);
    const float2 dd = *(const float2*)&denws[icb * NPIX + j0];
    d0 += dd.x; d1 += dd.y;
  }
  const float r0 = 1.f / d0, r1 = 1.f / d1;
#pragma unroll
  for (int e = 0; e < 4; ++e) {
    const int c = 4 * q + e;
    const size_t o = ((size_t)b * NC + c) * NPIX + j0;
    float2 z2;
    z2.x = bev[o] + n0[e] * r0;
    z2.y = bev[o + 1] + n1[e] * r1;
    *(float2*)&out[o] = z2;
  }
}

extern "C" void kernel_launch(void* const* d_in, const int* in_sizes, int n_in,
                              void* d_out, int out_size, void* d_ws, size_t ws_size,
                              hipStream_t stream) {
  const float* rv  = (const float*)d_in[0];
  const float* bev = (const float*)d_in[1];
  const float* Wq  = (const float*)d_in[2];
  const float* bq  = (const float*)d_in[3];
  const float* Wk  = (const float*)d_in[4];
  const float* bk  = (const float*)d_in[5];
  const float* Wv  = (const float*)d_in[6];
  const float* bv  = (const float*)d_in[7];
  float* out = (float*)d_out;

  short* qbf = (short*)d_ws;
  short* kbf = qbf + (size_t)NB * NPIX * 8;
  short* vbf = kbf + (size_t)NB * NPIX * 8;
  float* denws = (float*)(vbf + (size_t)NB * NPIX * 64);

  const size_t fixed = (size_t)NB * NPIX * (8 + 8 + 64) * 2;  // qkv bytes
  int nic = 8;
  while (nic > 2) {
    size_t need = fixed + (size_t)nic * NB * NPIX * 4                // denws
                        + (size_t)nic * NB * JB9 * 8 * 1024 * 4;     // numws
    if (need <= ws_size) break;
    nic >>= 1;
  }
  unsigned* numws = (unsigned*)(denws + (size_t)nic * NB * NPIX);

  cvt_qkv_kernel<<<dim3(144, NB), 512, 0, stream>>>(
      rv, bev, Wq, bq, Wk, bk, Wv, bv, qbf, kbf, vbf);
  const int nblk = nic * NB * JB9;
  if (nic == 8) {
    attn_kernel<18><<<dim3(nblk), 512, 0, stream>>>(qbf, kbf, vbf, numws, denws);
  } else if (nic == 4) {
    attn_kernel<36><<<dim3(nblk), 512, 0, stream>>>(qbf, kbf, vbf, numws, denws);
  } else {
    attn_kernel<72><<<dim3(nblk), 512, 0, stream>>>(qbf, kbf, vbf, numws, denws);
  }
  combine_kernel<<<dim3(288, NB), 256, 0, stream>>>(
      bev, numws, denws, out, nic);
}

// Round 11
// 76.217 us; speedup vs baseline: 1.2480x; 1.0032x over previous
//
#include <hip/hip_runtime.h>
#include <hip/hip_bf16.h>

#define NPIX 9216      // H*W
#define NB 2
#define NC 64
#define JB 72          // 128-j blocks per (b,ic)

typedef __attribute__((ext_vector_type(4))) short s16x4;
typedef __attribute__((ext_vector_type(8))) short s16x8;
typedef __attribute__((ext_vector_type(2))) float f32x2;
typedef __attribute__((ext_vector_type(4))) float fp32x4;
typedef __attribute__((ext_vector_type(16))) float f32x16;

#define LOG2E 1.44269504088896340736f

__device__ __forceinline__ float exp2fast(float x) {
#if defined(__has_builtin) && __has_builtin(__builtin_amdgcn_exp2f)
  return __builtin_amdgcn_exp2f(x);
#else
  float r; asm("v_exp_f32 %0, %1" : "=v"(r) : "v"(x)); return r;
#endif
}
#define EXP2(x) exp2fast(x)

__device__ __forceinline__ short bf16b(float f) {
  unsigned u = __builtin_bit_cast(unsigned, f);
  u += 0x7FFFu + ((u >> 16) & 1u);          // RNE, no NaN in this data
  return (short)(u >> 16);
}

__device__ __forceinline__ unsigned cvtpk(float a, float b) {
  unsigned r;
  asm("v_cvt_pk_bf16_f32 %0, %1, %2" : "=v"(r) : "v"(a), "v"(b));
  return r;
}

// Direct global->LDS DMA, 16B per lane. lds base must be wave-uniform.
__device__ __forceinline__ void gload_lds16(const void* g, void* l) {
  __builtin_amdgcn_global_load_lds(
      (const __attribute__((address_space(1))) unsigned*)g,
      (__attribute__((address_space(3))) unsigned*)l, 16, 0, 0);
}

// ---------------- Stage 1: per-pixel 1x1 convs -> q (pre-scaled by log2e), k
// (bf16 [b][pix][8]) and V packed for the 32x32x16 PV-MFMA B-operand:
// vbf[b][blk=i/32][ks2][s2][c64][t8], i = 32*blk + 16*ks + 4*s + (t&3) + 8*(t>>2).
// r11: bev tile ALSO staged in LDS (kills the 64-deep serial strided chain).
__global__ __launch_bounds__(512) void cvt_qkv_kernel(
    const float* __restrict__ rv, const float* __restrict__ bev,
    const float* __restrict__ Wq, const float* __restrict__ bq,
    const float* __restrict__ Wk, const float* __restrict__ bk,
    const float* __restrict__ Wv, const float* __restrict__ bv,
    short* __restrict__ qbf, short* __restrict__ kbf, short* __restrict__ vbf)
{
  __shared__ float wlds[5120];            // Wv @0, Wq*log2e @4096, Wk @4608
  __shared__ __align__(16) float xlds[64 * 68];   // rv tile [c][j], pad 68
  __shared__ __align__(16) float ylds[64 * 68];   // bev tile [c][j], pad 68
  __shared__ short vlds[64][72];          // v transpose buffer [c][j] (+pad)
  const int tid = threadIdx.x;
  const int jb = blockIdx.x, b = blockIdx.y;
  const int jbase = jb * 64;

  for (int idx = tid; idx < 5120; idx += 512)
    wlds[idx] = (idx < 4096) ? Wv[idx]
              : (idx < 4608) ? Wq[idx - 4096] * LOG2E
                             : Wk[idx - 4608];
  {
    const int sc = tid >> 3, sk = tid & 7;
    const size_t off = (size_t)b * NC * NPIX + (size_t)sc * NPIX + jbase + sk * 8;
    const float* srcr = rv + off;
    const float* srcb = bev + off;
    *(float4*)&xlds[sc * 68 + sk * 8]     = *(const float4*)(srcr);
    *(float4*)&xlds[sc * 68 + sk * 8 + 4] = *(const float4*)(srcr + 4);
    *(float4*)&ylds[sc * 68 + sk * 8]     = *(const float4*)(srcb);
    *(float4*)&ylds[sc * 68 + sk * 8 + 4] = *(const float4*)(srcb + 4);
  }
  __syncthreads();

  const int jl = tid & 63, cg = tid >> 6;   // cg 0..7

  float va[8];
#pragma unroll
  for (int u = 0; u < 8; ++u) va[u] = bv[cg * 8 + u];
  float qk[8];
  if (cg == 0) {
#pragma unroll
    for (int u = 0; u < 8; ++u) qk[u] = bq[u] * LOG2E;
  } else if (cg == 1) {
#pragma unroll
    for (int u = 0; u < 8; ++u) qk[u] = bk[u];
  }

  for (int c2 = 0; c2 < 32; ++c2) {
    const int c = c2 * 2;
    const float x0 = xlds[c * 68 + jl], x1 = xlds[(c + 1) * 68 + jl];
#pragma unroll
    for (int u = 0; u < 8; ++u) {
      float2 w = *(const float2*)&wlds[(cg * 8 + u) * 64 + c];
      va[u] = fmaf(w.y, x1, fmaf(w.x, x0, va[u]));
    }
    if (cg == 0) {
      const float y0 = ylds[c * 68 + jl], y1 = ylds[(c + 1) * 68 + jl];
#pragma unroll
      for (int u = 0; u < 8; ++u) {
        float2 w = *(const float2*)&wlds[4096 + u * 64 + c];
        qk[u] = fmaf(w.y, y1, fmaf(w.x, y0, qk[u]));
      }
    } else if (cg == 1) {
#pragma unroll
      for (int u = 0; u < 8; ++u) {
        float2 w = *(const float2*)&wlds[4608 + u * 64 + c];
        qk[u] = fmaf(w.y, x1, fmaf(w.x, x0, qk[u]));
      }
    }
  }

  if (cg == 0) {
    s16x8 qp;
#pragma unroll
    for (int u = 0; u < 8; ++u) qp[u] = bf16b(qk[u]);
    ((s16x8*)qbf)[(size_t)b * NPIX + jbase + jl] = qp;
  } else if (cg == 1) {
    s16x8 kp;
#pragma unroll
    for (int u = 0; u < 8; ++u) kp[u] = bf16b(qk[u]);
    ((s16x8*)kbf)[(size_t)b * NPIX + jbase + jl] = kp;
  }
#pragma unroll
  for (int u = 0; u < 8; ++u) vlds[cg * 8 + u][jl] = bf16b(va[u]);
  __syncthreads();

  s16x8* vout = (s16x8*)vbf + ((size_t)b * 288 + jb * 2) * 256;
  const int blk_l = tid >> 8;               // which 32-i block of the 64 pix
  const int rem = tid & 255;
  const int ks = rem >> 7, s = (rem >> 6) & 1, c = rem & 63;
  const int i0 = blk_l * 32 + ks * 16 + s * 4;
  s16x8 vv;
#pragma unroll
  for (int t = 0; t < 8; ++t)
    vv[t] = vlds[c][i0 + (t & 3) + 8 * (t >> 2)];
  vout[blk_l * 256 + (ks * 2 + s) * 64 + c] = vv;
}

// ---------------- Stage 2: flash attention, 32x32x16.
// r11: Block = 256 threads = 4 waves (was 8) -> 1152 blocks, ~4.5 blocks/CU,
// LDS 18.4 KB and wave-cap both allow 8 blocks/CU -> ~2x resident waves.
// Wave owns ONE 32-j tile (jbase = jb*128 + wid*32), full 64-c accumulation.
// V + q staged per 64-i chunk via global_load_lds, double buffered, one
// barrier per chunk; all 4 waves share the staged V.
// numws (bf16 pairs, native fragment layout):
//   addr = ((icb*72+jb)*4+wid)*1024 + u*64 + lane  (uint)
//   with jj=j&31: u = (jj>>3)*2 + ((jj>>1)&1) + 8*(c>>5);
//   lane = ((jj>>2)&1)*32 + (c&31); pair = (j even -> lo16, j odd -> hi16).
template <int NCH>   // NCH = number of 64-i chunks per ic
__global__ __launch_bounds__(256) void attn_kernel(
    const short* __restrict__ qbf, const short* __restrict__ kbf,
    const short* __restrict__ vbf,
    unsigned* __restrict__ numws, float* __restrict__ denws)
{
  __shared__ s16x8 lv[2][512];   // 16 KB: per chunk 2 units x [ks2][s2][c64]
  __shared__ s16x8 lq[2][64];    // 2 KB: 64 q rows (16B each)

  const int bid = blockIdx.x;
  const int jb = bid % JB;
  const int rest = bid / JB;
  const int b = rest % NB;
  const int ic = rest / NB;
  const int tid = threadIdx.x;        // 0..255
  const int wid = tid >> 6, lane = tid & 63;
  const int l31 = lane & 31, hi = lane >> 5;
  const int jbase = jb * 128 + wid * 32;
  const int ibase = ic * (NCH * 64);

  const s16x8* q8 = (const s16x8*)qbf + (size_t)b * NPIX;
  const short* krow = kbf + (size_t)b * NPIX * 8;
  const s16x8* v8 = (const s16x8*)vbf + (size_t)b * 288 * 256;

  const f32x16 z16 = {0.f};

  // Score B-operand (wave-fixed): lane (j=l31, s=hi): elems 0-3 =
  // k[jbase+l31][4hi..4hi+3], elems 4-7 = ZERO (k>=8 of the K=16 MFMA).
  s16x8 kf;
  {
    const s16x4 ka = *(const s16x4*)(krow + (size_t)(jbase + l31) * 8 + hi * 4);
    kf[0] = ka[0]; kf[1] = ka[1]; kf[2] = ka[2]; kf[3] = ka[3];
    kf[4] = 0; kf[5] = 0; kf[6] = 0; kf[7] = 0;
  }

  f32x16 acc0 = z16, acc1 = z16;
  f32x2 dA = {0.f, 0.f};
  const int vl = hi * 64 + l31;

  auto stage = [&](int ch, int bf) {
    const size_t ebase = ((size_t)(ibase >> 5) + ch * 2) * 256;  // s16x8 entries
    gload_lds16(&v8[ebase + wid * 64 + lane], &lv[bf][wid * 64]);
    gload_lds16(&v8[ebase + 256 + wid * 64 + lane], &lv[bf][256 + wid * 64]);
    if (wid == 0)
      gload_lds16(&q8[(size_t)ibase + ch * 64 + lane], &lq[bf][0]);
  };

  stage(0, 0);
  __syncthreads();           // drains vmcnt(0): buf0 staged

  int buf = 0;
  for (int ch = 0; ch < NCH; ++ch) {
    if (ch + 1 < NCH) stage(ch + 1, buf ^ 1);   // loads fly under compute
#pragma unroll
    for (int u = 0; u < 2; ++u) {
      const s16x4 qh = *(const s16x4*)((const short*)&lq[buf][0] + (u * 32 + l31) * 8 + hi * 4);
      s16x8 af;
      af[0] = qh[0]; af[1] = qh[1]; af[2] = qh[2]; af[3] = qh[3];
      af[4] = 0; af[5] = 0; af[6] = 0; af[7] = 0;
      const s16x8 vf00 = lv[buf][u * 256 + vl];          // ks0, c 0-31
      const s16x8 vf01 = lv[buf][u * 256 + 32 + vl];     // ks0, c 32-63
      const s16x8 vf10 = lv[buf][u * 256 + 128 + vl];    // ks1, c 0-31
      const s16x8 vf11 = lv[buf][u * 256 + 160 + vl];    // ks1, c 32-63

      const f32x16 S = __builtin_amdgcn_mfma_f32_32x32x16_bf16(af, kf, z16, 0, 0, 0);
      const float e0 = EXP2(S[0]),  e1 = EXP2(S[1]),  e2 = EXP2(S[2]),  e3 = EXP2(S[3]);
      const float e4 = EXP2(S[4]),  e5 = EXP2(S[5]),  e6 = EXP2(S[6]),  e7 = EXP2(S[7]);
      const float e8 = EXP2(S[8]),  e9 = EXP2(S[9]),  eA = EXP2(S[10]), eB = EXP2(S[11]);
      const float eC = EXP2(S[12]), eD = EXP2(S[13]), eE = EXP2(S[14]), eF = EXP2(S[15]);
      dA += (f32x2){e0, e1}; dA += (f32x2){e2, e3};
      dA += (f32x2){e4, e5}; dA += (f32x2){e6, e7};
      dA += (f32x2){e8, e9}; dA += (f32x2){eA, eB};
      dA += (f32x2){eC, eD}; dA += (f32x2){eE, eF};
      int4 p0i, p1i;
      p0i.x = cvtpk(e0, e1); p0i.y = cvtpk(e2, e3);
      p0i.z = cvtpk(e4, e5); p0i.w = cvtpk(e6, e7);
      p1i.x = cvtpk(e8, e9); p1i.y = cvtpk(eA, eB);
      p1i.z = cvtpk(eC, eD); p1i.w = cvtpk(eE, eF);
      const s16x8 A0 = __builtin_bit_cast(s16x8, p0i);   // i 0..15 of unit
      const s16x8 A1 = __builtin_bit_cast(s16x8, p1i);   // i 16..31
      acc0 = __builtin_amdgcn_mfma_f32_32x32x16_bf16(A0, vf00, acc0, 0, 0, 0);
      acc1 = __builtin_amdgcn_mfma_f32_32x32x16_bf16(A0, vf01, acc1, 0, 0, 0);
      acc0 = __builtin_amdgcn_mfma_f32_32x32x16_bf16(A1, vf10, acc0, 0, 0, 0);
      acc1 = __builtin_amdgcn_mfma_f32_32x32x16_bf16(A1, vf11, acc1, 0, 0, 0);
    }
    __syncthreads();         // all reads of buf done; next-stage loads drained
    buf ^= 1;
  }

  // den: lanes l and l^32 hold complementary i-subsets of the same j.
  float den = dA[0] + dA[1];
  den += __shfl_xor(den, 32);
  const size_t icb = (size_t)ic * NB + b;
  if (lane < 32) denws[icb * NPIX + jbase + l31] = den;

  // Tail: 16 coalesced uint stores in native fragment layout.
  const size_t wavebase = (((size_t)icb * JB + jb) * 4 + wid) * 1024;
#pragma unroll
  for (int qd = 0; qd < 4; ++qd) {
    numws[wavebase + (qd * 2 + 0) * 64 + lane] = cvtpk(acc0[4 * qd + 0], acc0[4 * qd + 1]);
    numws[wavebase + (qd * 2 + 1) * 64 + lane] = cvtpk(acc0[4 * qd + 2], acc0[4 * qd + 3]);
    numws[wavebase + (8 + qd * 2 + 0) * 64 + lane] = cvtpk(acc1[4 * qd + 0], acc1[4 * qd + 1]);
    numws[wavebase + (8 + qd * 2 + 1) * 64 + lane] = cvtpk(acc1[4 * qd + 2], acc1[4 * qd + 3]);
  }
}

// ---------------- Stage 3: combine i-splits, normalize, add residual.
// Decode verified in r10. For output (c, j): jj = j&31:
//   u = (jj>>3)*2 + ((jj>>1)&1) + 8*(c>>5);
//   lane = ((jj>>2)&1)*32 + (c&31); pair sel = j&1 (even->lo16, odd->hi16).
// Thread = one j-pair x 4 consecutive c; NIC templated -> unrolled loads.
template <int NIC>
__global__ __launch_bounds__(256) void combine_kernel(
    const float* __restrict__ bev, const unsigned* __restrict__ numws,
    const float* __restrict__ denws, float* __restrict__ out)
{
  const int tid = threadIdx.x;
  const int m = tid & 15;          // j-pair within the 32-j tile: jj = 2m, 2m+1
  const int q = tid >> 4;          // c-quad: c = 4q .. 4q+3
  const int b = blockIdx.y;
  const int j0 = blockIdx.x * 32 + 2 * m;       // even j
  const int jb = j0 >> 7, wid = (j0 >> 5) & 3;
  const int u = (m >> 2) * 2 + (m & 1) + 8 * (q >> 3);
  const int laneoff = ((m >> 1) & 1) * 32 + 4 * (q & 7);

  float n0[4] = {0.f, 0.f, 0.f, 0.f}, n1[4] = {0.f, 0.f, 0.f, 0.f};
  float d0 = 0.f, d1 = 0.f;
#pragma unroll
  for (int ic = 0; ic < NIC; ++ic) {
    const size_t icb = (size_t)ic * NB + b;
    const size_t base = (((icb * JB + jb) * 4 + wid) * 1024) + u * 64 + laneoff;
    const uint4 un = *(const uint4*)&numws[base];
    n0[0] += __builtin_bit_cast(float, un.x << 16);
    n1[0] += __builtin_bit_cast(float, un.x & 0xFFFF0000u);
    n0[1] += __builtin_bit_cast(float, un.y << 16);
    n1[1] += __builtin_bit_cast(float, un.y & 0xFFFF0000u);
    n0[2] += __builtin_bit_cast(float, un.z << 16);
    n1[2] += __builtin_bit_cast(float, un.z & 0xFFFF0000u);
    n0[3] += __builtin_bit_cast(float, un.w << 16);
    n1[3] += __builtin_bit_cast(float, un.w & 0xFFFF0000u);
    const float2 dd = *(const float2*)&denws[icb * NPIX + j0];
    d0 += dd.x; d1 += dd.y;
  }
  const float r0 = 1.f / d0, r1 = 1.f / d1;
#pragma unroll
  for (int e = 0; e < 4; ++e) {
    const int c = 4 * q + e;
    const size_t o = ((size_t)b * NC + c) * NPIX + j0;
    float2 z2;
    z2.x = bev[o] + n0[e] * r0;
    z2.y = bev[o + 1] + n1[e] * r1;
    *(float2*)&out[o] = z2;
  }
}

extern "C" void kernel_launch(void* const* d_in, const int* in_sizes, int n_in,
                              void* d_out, int out_size, void* d_ws, size_t ws_size,
                              hipStream_t stream) {
  const float* rv  = (const float*)d_in[0];
  const float* bev = (const float*)d_in[1];
  const float* Wq  = (const float*)d_in[2];
  const float* bq  = (const float*)d_in[3];
  const float* Wk  = (const float*)d_in[4];
  const float* bk  = (const float*)d_in[5];
  const float* Wv  = (const float*)d_in[6];
  const float* bv  = (const float*)d_in[7];
  float* out = (float*)d_out;

  short* qbf = (short*)d_ws;
  short* kbf = qbf + (size_t)NB * NPIX * 8;
  short* vbf = kbf + (size_t)NB * NPIX * 8;
  float* denws = (float*)(vbf + (size_t)NB * NPIX * 64);

  const size_t fixed = (size_t)NB * NPIX * (8 + 8 + 64) * 2;  // qkv bytes
  int nic = 8;
  while (nic > 2) {
    size_t need = fixed + (size_t)nic * NB * NPIX * 4                // denws
                        + (size_t)nic * NB * JB * 4 * 1024 * 4;      // numws
    if (need <= ws_size) break;
    nic >>= 1;
  }
  unsigned* numws = (unsigned*)(denws + (size_t)nic * NB * NPIX);

  cvt_qkv_kernel<<<dim3(144, NB), 512, 0, stream>>>(
      rv, bev, Wq, bq, Wk, bk, Wv, bv, qbf, kbf, vbf);
  const int nblk = nic * NB * JB;
  if (nic == 8) {
    attn_kernel<18><<<dim3(nblk), 256, 0, stream>>>(qbf, kbf, vbf, numws, denws);
    combine_kernel<8><<<dim3(288, NB), 256, 0, stream>>>(bev, numws, denws, out);
  } else if (nic == 4) {
    attn_kernel<36><<<dim3(nblk), 256, 0, stream>>>(qbf, kbf, vbf, numws, denws);
    combine_kernel<4><<<dim3(288, NB), 256, 0, stream>>>(bev, numws, denws, out);
  } else {
    attn_kernel<72><<<dim3(nblk), 256, 0, stream>>>(qbf, kbf, vbf, numws, denws);
    combine_kernel<2><<<dim3(288, NB), 256, 0, stream>>>(bev, numws, denws, out);
  }
}